// Round 2
// baseline (208.192 us; speedup 1.0000x reference)
//
#include <hip/hip_runtime.h>

// VQ layer, B=16, D=64, T=8192, E=512.
// Round 2: bitwise emulation of the numpy float32 reference pipeline.
//   s1  = np.sum(z*z, axis=1)        -> pairwise-8 (numpy pairwise_sum, n=64)
//   G   = z @ cb (sgemm)             -> sequential-k fp32 FMA chain, acc from 0
//   c2  = np.sum(cb*cb, axis=0)      -> sequential outer-axis accumulation
//   key = (s1 - 2*G) + c2            -> left-assoc, each op rounded fp32
//   id  = first-index strict min scan (== np.argmax(-dist2))
// All sensitive ops via __fmaf_rn/__fmul_rn/__fadd_rn/__fsub_rn (no contraction).

constexpr int Dc = 64;
constexpr int Ec = 512;
constexpr int Tc = 8192;
constexpr int Bc = 16;
constexpr int QTOT = Bc * Tc;          // 131072
constexpr int ZQ_ELEMS = Bc * Dc * Tc; // 8388608

__global__ __launch_bounds__(256) void vq_np_kernel(
    const float* __restrict__ z,       // [B, D, T]
    const float* __restrict__ cbfull,  // [4, D, E]
    const int*   __restrict__ cbidx,   // low word of int64 scalar
    float* __restrict__ out)           // z_q [B,D,T] ++ z_id [B,T] (float)
{
    __shared__ float s_c2[Ec];

    const int tid = threadIdx.x;
    const int q = blockIdx.x * 256 + tid;   // T%256==0 -> no batch straddle
    const int b = q >> 13;
    const int t = q & (Tc - 1);

    const int ci = cbidx[0] & 3;
    const float* __restrict__ cb = cbfull + (size_t)ci * (Dc * Ec); // [D, E]

    // c2[j]: numpy outer-axis reduce -> sequential over d, separate mul/add.
    for (int j = tid; j < Ec; j += 256) {
        float c = cb[j];
        float acc = __fmul_rn(c, c);
        for (int d = 1; d < Dc; ++d) {
            c = cb[d * Ec + j];
            acc = __fadd_rn(acc, __fmul_rn(c, c));
        }
        s_c2[j] = acc;
    }
    __syncthreads();

    // query vector -> registers (coalesced: lanes adjacent in t)
    const float* __restrict__ zp = z + (size_t)b * (Dc * Tc) + t;
    float zv[Dc];
    #pragma unroll
    for (int d = 0; d < Dc; ++d) zv[d] = zp[(size_t)d * Tc];

    // s1: numpy pairwise_sum, n=64 path (8 accumulators + fixed combine tree)
    float r[8];
    #pragma unroll
    for (int u = 0; u < 8; ++u) r[u] = __fmul_rn(zv[u], zv[u]);
    #pragma unroll
    for (int i = 8; i < 64; i += 8) {
        #pragma unroll
        for (int u = 0; u < 8; ++u)
            r[u] = __fadd_rn(r[u], __fmul_rn(zv[i + u], zv[i + u]));
    }
    const float s1 = __fadd_rn(
        __fadd_rn(__fadd_rn(r[0], r[1]), __fadd_rn(r[2], r[3])),
        __fadd_rn(__fadd_rn(r[4], r[5]), __fadd_rn(r[6], r[7])));

    float best = __int_as_float(0x7f800000);  // +inf
    int bestIdx = 0;

    #pragma unroll 1
    for (int jb = 0; jb < Ec; jb += 8) {
        float acc[8];
        #pragma unroll
        for (int u = 0; u < 8; ++u) acc[u] = 0.0f;
        // sgemm: sequential-k FMA chain; cb index is wave-uniform -> s_load
        #pragma unroll
        for (int d = 0; d < Dc; ++d) {
            const float zd = zv[d];
            #pragma unroll
            for (int u = 0; u < 8; ++u)
                acc[u] = __fmaf_rn(zd, cb[d * Ec + jb + u], acc[u]);
        }
        #pragma unroll
        for (int u = 0; u < 8; ++u) {
            const float key = __fadd_rn(__fsub_rn(s1, __fmul_rn(2.0f, acc[u])),
                                        s_c2[jb + u]);
            if (key < best) { best = key; bestIdx = jb + u; }  // first-index min
        }
    }

    // z_q[b,:,t] = cb[:,bestIdx] (exact fp32 copies; L2-hot 128KB codebook)
    float* __restrict__ op = out + (size_t)b * (Dc * Tc) + t;
    #pragma unroll
    for (int d = 0; d < Dc; ++d) op[(size_t)d * Tc] = cb[d * Ec + bestIdx];

    out[ZQ_ELEMS + q] = (float)bestIdx;
}

extern "C" void kernel_launch(void* const* d_in, const int* in_sizes, int n_in,
                              void* d_out, int out_size, void* d_ws, size_t ws_size,
                              hipStream_t stream) {
    const float* z      = (const float*)d_in[0];
    const float* cbfull = (const float*)d_in[1];
    const int*   cbidx  = (const int*)d_in[2];
    float* out = (float*)d_out;

    dim3 grid(QTOT / 256), block(256);
    hipLaunchKernelGGL(vq_np_kernel, grid, block, 0, stream, z, cbfull, cbidx, out);
}